// Round 12
// baseline (681.729 us; speedup 1.0000x reference)
//
#include <hip/hip_runtime.h>

// RegistrationLoss: sim = -mean(NCC_9x9x9(warped, fixed)), reg = bending energy of flow,
// total = sim + 0.01*reg. Inputs f32: warped[2,1,128,128,128], fixed same, flow[2,3,128,128,128].
// Output: 3 floats [total, sim, reg].
//
// Round-12 structure (occupancy-step fix):
//   HW fact (MI355X): waves/CU halves at VGPR={64,128,256} -> VGPR 65..128 gives only
//   4 waves/SIMD. R9(88 VGPR, LDS) and R11(88 VGPR, DPP) ran identically at VALUBusy 42%
//   because both sat at 4 waves/SIMD with ~58% issue-idle. Fix: <=64 VGPR + >=8192 waves.
//   wh_bend: h-chunk=4 (8192 waves / 2048 blocks), NO ring — 4 output accumulators
//            (acc[4][5] float2 = 40 regs); per step, per field: center product ->
//            4 DPP lane-shifts (wave_shr/shl, zero-fill == zero-pad) -> 9-wide W-sum ->
//            add into the <=4 covering H-windows (static unrolled bounds). Store 4 rows
//            packed bf16 at end. THEN bending phase (6 grid-strided float4 iters).
//            __launch_bounds__(256,8) pins VGPR=64. Spill tripwire: WRITE_SIZE >> 41 MB.
//   ncc_d:  same accumulator treatment, d-seg=4 (8192 waves / 2048 blocks), rs[4][5].
// bufB row layout (per (b,d,h), 320 unsigned = 1280 B):
//   [0,256): uint4{bf2(f0),bf2(f1),bf2(f2),bf2(f3)} per w-pair at 4*wp
//   [256,320): bf2(f4) dword per w-pair
// Lessons kept: no per-LANE conditional loads (R5); no block-type mixing (R7);
// accumulator indices all compile-time (rule #20).

#define DIM 128
#define V   4194304L      // 2*128^3
#define NVOL6 12582912L   // 6*128^3

#define ZER2 make_float2(0.f, 0.f)

__device__ __forceinline__ unsigned pack_bf2(float2 v) {
    unsigned ax = __float_as_uint(v.x), ay = __float_as_uint(v.y);
    ax = ax + 0x7fffu + ((ax >> 16) & 1u);      // round-to-nearest-even
    ay = ay + 0x7fffu + ((ay >> 16) & 1u);
    return (ax >> 16) | (ay & 0xffff0000u);
}
__device__ __forceinline__ float2 unpack_bf2(unsigned u) {
    return make_float2(__uint_as_float(u << 16), __uint_as_float(u & 0xffff0000u));
}

// DPP wave-wide lane shifts. wave_shr:1 (0x138): lane i <- lane i-1 (lane 0 -> 0).
// wave_shl:1 (0x130): lane i <- lane i+1 (lane 63 -> 0). bound_ctrl=true: zero-fill.
__device__ __forceinline__ float dpp_up1(float x) {
    return __int_as_float(__builtin_amdgcn_mov_dpp(__float_as_int(x), 0x138, 0xF, 0xF, true));
}
__device__ __forceinline__ float dpp_dn1(float x) {
    return __int_as_float(__builtin_amdgcn_mov_dpp(__float_as_int(x), 0x130, 0xF, 0xF, true));
}
__device__ __forceinline__ float2 dpp_up1_f2(float2 v) {
    return make_float2(dpp_up1(v.x), dpp_up1(v.y));
}
__device__ __forceinline__ float2 dpp_dn1_f2(float2 v) {
    return make_float2(dpp_dn1(v.x), dpp_dn1(v.y));
}

__device__ __forceinline__ float wave_block_reduce_partial(float local, float* lds, int t, int nwaves) {
    #pragma unroll
    for (int off = 32; off > 0; off >>= 1) local += __shfl_down(local, off, 64);
    if ((t & 63) == 0) lds[t >> 6] = local;
    __syncthreads();
    float s = 0.f;
    if (t == 0) {
        for (int i = 0; i < nwaves; ++i) s += lds[i];
    }
    return s; // valid on t==0 only
}

// ---------------- Kernel 1: ncc_wh phase (accumulator form) + bending phase ----------------
__global__ __launch_bounds__(256, 8) void wh_bend(const float* __restrict__ I,
                                                  const float* __restrict__ J,
                                                  const float* __restrict__ F,
                                                  unsigned* __restrict__ bufB,
                                                  float* __restrict__ regPartial) {
    // ================= phase 1: products + W-box + H-box -> bufB =================
    {
        const int lane = threadIdx.x & 63;
        const int wv   = threadIdx.x >> 6;
        const int wid  = (blockIdx.x << 2) + wv;   // [0, 8192)
        const int e = wid & 31;           // h-chunk of 4
        const int d = (wid >> 5) & 127;
        const int b = wid >> 12;
        const int h0 = e << 2;
        const int w0 = lane << 1;
        const float* baseI = I + (b * 128 + d) * 16384 + w0;
        const float* baseJ = J + (b * 128 + d) * 16384 + w0;

        float2 acc[4][5];
        #pragma unroll
        for (int k = 0; k < 4; ++k)
            #pragma unroll
            for (int f = 0; f < 5; ++f) acc[k][f] = ZER2;

        // 1-step prefetch of the center float2 (wave-uniform row guard; invalid row -> 0,
        // and box-of-zeros contributes 0 == zero-pad semantics)
        float2 na = ZER2, nb = ZER2;
        {
            const int h = h0 - 4;
            if ((unsigned)h < 128u) {
                na = *reinterpret_cast<const float2*>(baseI + h * 128);
                nb = *reinterpret_cast<const float2*>(baseJ + h * 128);
            }
        }

        #pragma unroll
        for (int s = 0; s < 12; ++s) {
            const float2 ci = na, cj = nb;
            if (s < 11) {
                const int h = h0 - 3 + s;
                if ((unsigned)h < 128u) {
                    na = *reinterpret_cast<const float2*>(baseI + h * 128);
                    nb = *reinterpret_cast<const float2*>(baseJ + h * 128);
                } else {
                    na = ZER2; nb = ZER2;
                }
            }

            const int klo = (s > 8) ? (s - 8) : 0;   // compile-time per unrolled s
            const int khi = (s < 3) ? s : 3;

            #pragma unroll
            for (int f = 0; f < 5; ++f) {
                float2 x;
                if      (f == 0) x = ci;
                else if (f == 1) x = cj;
                else if (f == 2) x = make_float2(ci.x * ci.x, ci.y * ci.y);
                else if (f == 3) x = make_float2(cj.x * cj.x, cj.y * cj.y);
                else             x = make_float2(ci.x * cj.x, ci.y * cj.y);

                const float2 s1 = dpp_up1_f2(x);     // elements w-2,w-1
                const float2 s0 = dpp_up1_f2(s1);    // w-4,w-3
                const float2 s3 = dpp_dn1_f2(x);     // w+2,w+3
                const float2 s4 = dpp_dn1_f2(s3);    // w+4,w+5

                const float core = s1.x + s1.y + x.x + x.y + s3.x + s3.y;
                const float wbx = core + s0.x + s0.y + s4.x;   // window w-4..w+4
                const float wby = core + s0.y + s4.x + s4.y;   // window w-3..w+5

                #pragma unroll
                for (int k = klo; k <= khi; ++k) {
                    acc[k][f].x += wbx; acc[k][f].y += wby;
                }
            }
        }

        // store 4 output rows (packed bf16)
        #pragma unroll
        for (int k = 0; k < 4; ++k) {
            unsigned* row = bufB + ((b * 128 + d) * 128 + (h0 + k)) * 320;
            const uint4 pk = make_uint4(pack_bf2(acc[k][0]), pack_bf2(acc[k][1]),
                                        pack_bf2(acc[k][2]), pack_bf2(acc[k][3]));
            *reinterpret_cast<uint4*>(row + 4 * lane) = pk;
            row[256 + lane] = pack_bf2(acc[k][4]);
        }
    }

    // ================= phase 2: bending energy (tail-fill, grid-strided) =================
    {
        const float invS = 1.0f / 12386304.0f;   // 6*126*128*128  (i==j)
        const float invC = 1.0f / 12289536.0f;   // 6*127*126*128  (i!=j, both orderings)
        float local = 0.f;

        #pragma unroll 2
        for (int it = 0; it < 6; ++it) {
            const int tid = (blockIdx.x + it * 2048) * 256 + threadIdx.x;  // [0, 3145728)
            const long e = (long)tid << 2;                                  // element base
            const int r = (int)(e & 2097151);
            const int d = r >> 14;
            const int h = (r >> 7) & 127;
            const int w0 = r & 127;                                         // 0,4,...,124

            const float* p = F + e;
            const int off4 = (w0 < 124) ? 4 : 0;
            const int oD  = (d < 127) ? 16384 : 0;
            const int oD2 = (d < 126) ? 32768 : 0;
            const int oH  = (h < 127) ? 128 : 0;
            const int oH2 = (h < 126) ? 256 : 0;

            const float4 a0  = *reinterpret_cast<const float4*>(p);
            const float2 s45 = *reinterpret_cast<const float2*>(p + off4);
            const float4 aD  = *reinterpret_cast<const float4*>(p + oD);
            const float  sD4 = (p + oD)[off4];
            const float4 aD2 = *reinterpret_cast<const float4*>(p + oD2);
            const float4 aH  = *reinterpret_cast<const float4*>(p + oH);
            const float  sH4 = (p + oH)[off4];
            const float4 aH2 = *reinterpret_cast<const float4*>(p + oH2);
            const float4 aDH = *reinterpret_cast<const float4*>(p + oD + oH);

            const float A0[6] = {a0.x, a0.y, a0.z, a0.w, s45.x, s45.y};
            const float AD[5] = {aD.x, aD.y, aD.z, aD.w, sD4};
            const float AH[5] = {aH.x, aH.y, aH.z, aH.w, sH4};
            const float AD2[4] = {aD2.x, aD2.y, aD2.z, aD2.w};
            const float AH2[4] = {aH2.x, aH2.y, aH2.z, aH2.w};
            const float ADH[4] = {aDH.x, aDH.y, aDH.z, aDH.w};

            const float mD2 = (d < 126) ? invS : 0.f;
            const float mH2 = (h < 126) ? invS : 0.f;
            const float cD  = (d < 126) ? 1.f : 0.f;
            const float cH  = (h < 126) ? 1.f : 0.f;
            const bool  vD  = d < 127, vH = h < 127;

            #pragma unroll
            for (int k = 0; k < 4; ++k) {
                const int wk = w0 + k;
                const float mW2 = (wk < 126) ? invS : 0.f;
                const float cW  = (wk < 126) ? 1.f : 0.f;
                const bool  vW  = wk < 127;

                const float xW = A0[k + 2] - 2.f * A0[k + 1] + A0[k];
                local += xW * xW * mW2;
                const float xD = AD2[k] - 2.f * AD[k] + A0[k];
                local += xD * xD * mD2;
                const float xH = AH2[k] - 2.f * AH[k] + A0[k];
                local += xH * xH * mH2;

                const float xDH = ADH[k] - AD[k] - AH[k] + A0[k];
                local += xDH * xDH * (((vD && vH) ? (cD + cH) : 0.f) * invC);
                const float xDW = AD[k + 1] - AD[k] - A0[k + 1] + A0[k];
                local += xDW * xDW * (((vD && vW) ? (cD + cW) : 0.f) * invC);
                const float xHW = AH[k + 1] - AH[k] - A0[k + 1] + A0[k];
                local += xHW * xHW * (((vH && vW) ? (cH + cW) : 0.f) * invC);
            }
        }

        __shared__ float rl[4];
        const float s = wave_block_reduce_partial(local, rl, threadIdx.x, 4);
        if (threadIdx.x == 0) regPartial[blockIdx.x] = s;
    }
}

// ---------------- Kernel 2: D-box (accumulator form) + NCC + block reduce ----------------
// Block = (b, h, group of 8). 256 threads = w-pair(64) x 4 segs (sg wave-uniform).
// Each seg owns 4 d (d0..d0+3); 12 steps cover d0-4..d0+7; rs[4][5] accumulators.
__global__ __launch_bounds__(256, 8) void ncc_d(const unsigned* __restrict__ bufB,
                                                float* __restrict__ nccPartial) {
    const int t = threadIdx.x;
    const int wp = t & 63;             // w-pair index
    const int sg = t >> 6;             // 0..3 (wave-uniform)
    const int b = blockIdx.x >> 10;
    const int h = (blockIdx.x >> 3) & 127;
    const int g = blockIdx.x & 7;
    const int d0 = (((g << 2) + sg) << 2);   // owned d: d0..d0+3
    const float inv_n = 1.0f / 729.0f;

    float2 rs[4][5];
    #pragma unroll
    for (int k = 0; k < 4; ++k)
        #pragma unroll
        for (int f = 0; f < 5; ++f) rs[k][f] = ZER2;

    // 1-step prefetch of the 20 B row slice
    uint4 nx = make_uint4(0u, 0u, 0u, 0u);
    unsigned nx4 = 0u;
    {
        const int dd = d0 - 4;
        if ((unsigned)dd < 128u) {
            const unsigned* row = bufB + ((b * 128 + dd) * 128 + h) * 320;
            nx = *reinterpret_cast<const uint4*>(row + 4 * wp);
            nx4 = row[256 + wp];
        }
    }

    #pragma unroll
    for (int s = 0; s < 12; ++s) {
        const uint4 cx = nx;
        const unsigned cx4 = nx4;
        if (s < 11) {
            const int dd = d0 - 3 + s;
            if ((unsigned)dd < 128u) {
                const unsigned* row = bufB + ((b * 128 + dd) * 128 + h) * 320;
                nx = *reinterpret_cast<const uint4*>(row + 4 * wp);
                nx4 = row[256 + wp];
            } else {
                nx = make_uint4(0u, 0u, 0u, 0u); nx4 = 0u;
            }
        }

        const int klo = (s > 8) ? (s - 8) : 0;   // compile-time per unrolled s
        const int khi = (s < 3) ? s : 3;
        const unsigned xs[5] = {cx.x, cx.y, cx.z, cx.w, cx4};
        #pragma unroll
        for (int f = 0; f < 5; ++f) {
            const float2 nv = unpack_bf2(xs[f]);
            #pragma unroll
            for (int k = klo; k <= khi; ++k) {
                rs[k][f].x += nv.x; rs[k][f].y += nv.y;
            }
        }
    }

    float local = 0.f;
    #pragma unroll
    for (int k = 0; k < 4; ++k) {
        const float uix = rs[k][0].x * inv_n, uiy = rs[k][0].y * inv_n;
        const float ujx = rs[k][1].x * inv_n, ujy = rs[k][1].y * inv_n;
        const float i2x = rs[k][2].x * inv_n - uix * uix;
        const float i2y = rs[k][2].y * inv_n - uiy * uiy;
        const float j2x = rs[k][3].x * inv_n - ujx * ujx;
        const float j2y = rs[k][3].y * inv_n - ujy * ujy;
        const float ijx = rs[k][4].x * inv_n - uix * ujx;
        const float ijy = rs[k][4].y * inv_n - uiy * ujy;
        local += ijx * ijx / (i2x * j2x + 1e-5f)
               + ijy * ijy / (i2y * j2y + 1e-5f);
    }

    __shared__ float lds[4];
    const float s = wave_block_reduce_partial(local, lds, t, 4);
    if (t == 0) nccPartial[blockIdx.x] = s;
}

// ---------------- Finalize ----------------
__global__ void finalize(const float* __restrict__ nccPartial, const float* __restrict__ regPartial,
                         float* __restrict__ out) {
    __shared__ float sdata[256];
    const int t = threadIdx.x;
    float a = 0.f;
    for (int i = t; i < 2048; i += 256) a += nccPartial[i];
    sdata[t] = a; __syncthreads();
    for (int s = 128; s > 0; s >>= 1) { if (t < s) sdata[t] += sdata[t + s]; __syncthreads(); }
    const float nccSum = sdata[0];
    __syncthreads();
    float bsum = 0.f;
    for (int i = t; i < 2048; i += 256) bsum += regPartial[i];
    sdata[t] = bsum; __syncthreads();
    for (int s = 128; s > 0; s >>= 1) { if (t < s) sdata[t] += sdata[t + s]; __syncthreads(); }
    if (t == 0) {
        const float reg = sdata[0];
        const float sim = -nccSum / (float)V;
        out[0] = sim + 0.01f * reg;
        out[1] = sim;
        out[2] = reg;
    }
}

extern "C" void kernel_launch(void* const* d_in, const int* in_sizes, int n_in,
                              void* d_out, int out_size, void* d_ws, size_t ws_size,
                              hipStream_t stream) {
    const float* warped = (const float*)d_in[0];
    const float* fixedv = (const float*)d_in[1];
    const float* flow   = (const float*)d_in[2];
    float* out = (float*)d_out;
    float* ws  = (float*)d_ws;

    // ws layout (floats): [0,2048) nccPartial | [2048,4096) regPartial | pad |
    //                     [16384, ...) bufB packed bf16 (2*128^3*5*2B ~= 42 MB)
    float* nccPartial = ws;
    float* regPartial = ws + 2048;
    unsigned* bufB = (unsigned*)(ws + 16384);

    // 2048 blocks = 8192 wh-waves (wave = (b, d, h-chunk of 4)) + bending tail-fill
    wh_bend<<<dim3(2048), dim3(256), 0, stream>>>(warped, fixedv, flow, bufB, regPartial);
    // 2048 blocks = (b, h, group); 256 threads = w-pair x 4 d-segments of 4
    ncc_d<<<dim3(2048), dim3(256), 0, stream>>>(bufB, nccPartial);
    finalize<<<dim3(1), dim3(256), 0, stream>>>(nccPartial, regPartial, out);
}

// Round 13
// 75.329 us; speedup vs baseline: 9.0501x; 9.0501x over previous
//
#include <hip/hip_runtime.h>

// RegistrationLoss: sim = -mean(NCC_9x9x9(warped, fixed)), reg = bending energy of flow,
// total = sim + 0.01*reg. Inputs f32: warped[2,1,128,128,128], fixed same, flow[2,3,128,128,128].
// Output: 3 floats [total, sim, reg].
//
// Round-13 structure (R11 + instruction-level phase interleave):
//   R12 post-mortem: __launch_bounds__(256,8) pinned VGPR=32 -> 1.2 GB of spill traffic.
//   The wh live state (~88 regs; LLVM already converts the unrolled ring to accumulators)
//   cannot fit the 8-wave/SIMD step. Operating point is 4 waves/SIMD; the lever left is
//   intra-wave ILP.
//   wh_bend: per wh step s in [2,14): issue ONE bending float4-iteration's 9 loads at
//            step top, run wh's DPP/W-box/H-ring compute, then bending's ~24 VALU terms.
//            Each wave thus always has a second independent stream to issue during its
//            own VMEM waits. All conditions compile-time (full unroll). VGPR budget
//            ~115-125 < 128 cliff. Tripwire: VGPR>128 or WRITE >> 41 MB => void.
//   ncc_d:  R11's version (D-box ring, 1-step prefetch, uint4+dword loads).
// bufB row layout (per (b,d,h), 320 unsigned = 1280 B):
//   [0,256): uint4{bf2(f0),bf2(f1),bf2(f2),bf2(f3)} per w-pair at 4*wp
//   [256,320): bf2(f4) dword per w-pair
// Lessons kept: no min-waves launch_bounds (R4/R12); no per-LANE conditional loads (R5);
// no block-type mixing (R7); compile-time indices only (rule #20).

#define DIM 128
#define V   4194304L      // 2*128^3
#define NVOL6 12582912L   // 6*128^3

#define ZER2 make_float2(0.f, 0.f)

__device__ __forceinline__ unsigned pack_bf2(float2 v) {
    unsigned ax = __float_as_uint(v.x), ay = __float_as_uint(v.y);
    ax = ax + 0x7fffu + ((ax >> 16) & 1u);      // round-to-nearest-even
    ay = ay + 0x7fffu + ((ay >> 16) & 1u);
    return (ax >> 16) | (ay & 0xffff0000u);
}
__device__ __forceinline__ float2 unpack_bf2(unsigned u) {
    return make_float2(__uint_as_float(u << 16), __uint_as_float(u & 0xffff0000u));
}

// DPP wave-wide lane shifts. wave_shr:1 (0x138): lane i <- lane i-1 (lane 0 -> 0).
// wave_shl:1 (0x130): lane i <- lane i+1 (lane 63 -> 0). bound_ctrl=true: zero-fill.
__device__ __forceinline__ float dpp_up1(float x) {
    return __int_as_float(__builtin_amdgcn_mov_dpp(__float_as_int(x), 0x138, 0xF, 0xF, true));
}
__device__ __forceinline__ float dpp_dn1(float x) {
    return __int_as_float(__builtin_amdgcn_mov_dpp(__float_as_int(x), 0x130, 0xF, 0xF, true));
}
__device__ __forceinline__ float2 dpp_up1_f2(float2 v) {
    return make_float2(dpp_up1(v.x), dpp_up1(v.y));
}
__device__ __forceinline__ float2 dpp_dn1_f2(float2 v) {
    return make_float2(dpp_dn1(v.x), dpp_dn1(v.y));
}

__device__ __forceinline__ float wave_block_reduce_partial(float local, float* lds, int t, int nwaves) {
    #pragma unroll
    for (int off = 32; off > 0; off >>= 1) local += __shfl_down(local, off, 64);
    if ((t & 63) == 0) lds[t >> 6] = local;
    __syncthreads();
    float s = 0.f;
    if (t == 0) {
        for (int i = 0; i < nwaves; ++i) s += lds[i];
    }
    return s; // valid on t==0 only
}

// ---------------- Kernel 1: wh steps with interleaved bending iterations ----------------
__global__ __launch_bounds__(256) void wh_bend(const float* __restrict__ I,
                                               const float* __restrict__ J,
                                               const float* __restrict__ F,
                                               unsigned* __restrict__ bufB,
                                               float* __restrict__ regPartial) {
    const float invS = 1.0f / 12386304.0f;   // 6*126*128*128  (i==j)
    const float invC = 1.0f / 12289536.0f;   // 6*127*126*128  (i!=j, both orderings)

    // wh task setup
    const int lane = threadIdx.x & 63;
    const int wv   = threadIdx.x >> 6;
    const int wid  = (blockIdx.x << 2) + wv;   // [0, 4096)
    const int e = wid & 15;           // h-chunk of 8
    const int d = (wid >> 4) & 127;
    const int b = wid >> 11;
    const int h0 = e << 3;
    const int w0 = lane << 1;
    const float* baseI = I + (b * 128 + d) * 16384 + w0;
    const float* baseJ = J + (b * 128 + d) * 16384 + w0;

    float2 win[9][5];
    float2 hs[5];
    #pragma unroll
    for (int f = 0; f < 5; ++f) hs[f] = ZER2;

    float bendAcc = 0.f;

    // 1-step prefetch of the center float2 (wave-uniform row guard)
    float2 na = ZER2, nb = ZER2;
    {
        const int h = h0 - 4;
        if ((unsigned)h < 128u) {
            na = *reinterpret_cast<const float2*>(baseI + h * 128);
            nb = *reinterpret_cast<const float2*>(baseJ + h * 128);
        }
    }

    #pragma unroll
    for (int s = 0; s < 16; ++s) {
        // ---- (1) bending loads for iteration it = s-2, issued early ----
        float4 ba0, baD, baD2, baH, baH2, baDH;
        float2 bs45;
        float  bsD4, bsH4;
        int bw0 = 0, bd = 0, bh = 0;
        if (s >= 2 && s < 14) {
            const int it = s - 2;
            const int tid = (blockIdx.x + it * 1024) * 256 + threadIdx.x;  // [0, 3145728)
            const long ee = (long)tid << 2;
            const int r = (int)(ee & 2097151);
            bd = r >> 14;
            bh = (r >> 7) & 127;
            bw0 = r & 127;

            const float* p = F + ee;
            const int off4 = (bw0 < 124) ? 4 : 0;
            const int oD  = (bd < 127) ? 16384 : 0;
            const int oD2 = (bd < 126) ? 32768 : 0;
            const int oH  = (bh < 127) ? 128 : 0;
            const int oH2 = (bh < 126) ? 256 : 0;

            ba0  = *reinterpret_cast<const float4*>(p);
            bs45 = *reinterpret_cast<const float2*>(p + off4);
            baD  = *reinterpret_cast<const float4*>(p + oD);
            bsD4 = (p + oD)[off4];
            baD2 = *reinterpret_cast<const float4*>(p + oD2);
            baH  = *reinterpret_cast<const float4*>(p + oH);
            bsH4 = (p + oH)[off4];
            baH2 = *reinterpret_cast<const float4*>(p + oH2);
            baDH = *reinterpret_cast<const float4*>(p + oD + oH);
        }

        // ---- (2) wh: rotate prefetch, issue next row loads ----
        const float2 ci = na, cj = nb;
        if (s < 15) {
            const int h = h0 - 3 + s;
            if ((unsigned)h < 128u) {
                na = *reinterpret_cast<const float2*>(baseI + h * 128);
                nb = *reinterpret_cast<const float2*>(baseJ + h * 128);
            } else {
                na = ZER2; nb = ZER2;
            }
        }

        // ---- (3) wh compute: DPP W-views, products, W-box, H-ring, store ----
        {
            float2 iv[5], jv[5];
            iv[2] = ci;                jv[2] = cj;
            iv[1] = dpp_up1_f2(ci);    jv[1] = dpp_up1_f2(cj);
            iv[0] = dpp_up1_f2(iv[1]); jv[0] = dpp_up1_f2(jv[1]);
            iv[3] = dpp_dn1_f2(ci);    jv[3] = dpp_dn1_f2(cj);
            iv[4] = dpp_dn1_f2(iv[3]); jv[4] = dpp_dn1_f2(jv[3]);

            float2 v[5][5];
            #pragma unroll
            for (int o = 0; o < 5; ++o) {
                v[0][o] = iv[o];
                v[1][o] = jv[o];
                v[2][o] = make_float2(iv[o].x * iv[o].x, iv[o].y * iv[o].y);
                v[3][o] = make_float2(jv[o].x * jv[o].x, jv[o].y * jv[o].y);
                v[4][o] = make_float2(iv[o].x * jv[o].x, iv[o].y * jv[o].y);
            }

            #pragma unroll
            for (int f = 0; f < 5; ++f) {
                const float core = v[f][1].x + v[f][1].y + v[f][2].x + v[f][2].y
                                 + v[f][3].x + v[f][3].y;
                float2 wb;
                wb.x = core + v[f][0].x + v[f][0].y + v[f][4].x;   // window w-4..w+4
                wb.y = core + v[f][0].y + v[f][4].x + v[f][4].y;   // window w-3..w+5
                if (s >= 9) { hs[f].x -= win[s % 9][f].x; hs[f].y -= win[s % 9][f].y; }
                hs[f].x += wb.x; hs[f].y += wb.y;
                win[s % 9][f] = wb;
            }

            if (s >= 8) {
                const int h_out = h0 + s - 8;
                unsigned* row = bufB + ((b * 128 + d) * 128 + h_out) * 320;
                const uint4 pk = make_uint4(pack_bf2(hs[0]), pack_bf2(hs[1]),
                                            pack_bf2(hs[2]), pack_bf2(hs[3]));
                *reinterpret_cast<uint4*>(row + 4 * lane) = pk;
                row[256 + lane] = pack_bf2(hs[4]);
            }
        }

        // ---- (4) bending compute for iteration it = s-2 ----
        if (s >= 2 && s < 14) {
            const float A0[6] = {ba0.x, ba0.y, ba0.z, ba0.w, bs45.x, bs45.y};
            const float AD[5] = {baD.x, baD.y, baD.z, baD.w, bsD4};
            const float AH[5] = {baH.x, baH.y, baH.z, baH.w, bsH4};
            const float AD2[4] = {baD2.x, baD2.y, baD2.z, baD2.w};
            const float AH2[4] = {baH2.x, baH2.y, baH2.z, baH2.w};
            const float ADH[4] = {baDH.x, baDH.y, baDH.z, baDH.w};

            const float mD2 = (bd < 126) ? invS : 0.f;
            const float mH2 = (bh < 126) ? invS : 0.f;
            const float cD  = (bd < 126) ? 1.f : 0.f;
            const float cH  = (bh < 126) ? 1.f : 0.f;
            const bool  vD  = bd < 127, vH = bh < 127;

            float local = 0.f;
            #pragma unroll
            for (int k = 0; k < 4; ++k) {
                const int wk = bw0 + k;
                const float mW2 = (wk < 126) ? invS : 0.f;
                const float cW  = (wk < 126) ? 1.f : 0.f;
                const bool  vW  = wk < 127;

                const float xW = A0[k + 2] - 2.f * A0[k + 1] + A0[k];
                local += xW * xW * mW2;
                const float xD = AD2[k] - 2.f * AD[k] + A0[k];
                local += xD * xD * mD2;
                const float xH = AH2[k] - 2.f * AH[k] + A0[k];
                local += xH * xH * mH2;

                const float xDH = ADH[k] - AD[k] - AH[k] + A0[k];
                local += xDH * xDH * (((vD && vH) ? (cD + cH) : 0.f) * invC);
                const float xDW = AD[k + 1] - AD[k] - A0[k + 1] + A0[k];
                local += xDW * xDW * (((vD && vW) ? (cD + cW) : 0.f) * invC);
                const float xHW = AH[k + 1] - AH[k] - A0[k + 1] + A0[k];
                local += xHW * xHW * (((vH && vW) ? (cH + cW) : 0.f) * invC);
            }
            bendAcc += local;
        }
    }

    __shared__ float rl[4];
    const float s = wave_block_reduce_partial(bendAcc, rl, threadIdx.x, 4);
    if (threadIdx.x == 0) regPartial[blockIdx.x] = s;
}

// ---------------- Kernel 2: D-box + NCC + block reduce (R11 version) ----------------
__global__ __launch_bounds__(256) void ncc_d(const unsigned* __restrict__ bufB,
                                             float* __restrict__ nccPartial) {
    const int t = threadIdx.x;
    const int wp = t & 63;             // w-pair index
    const int sg = t >> 6;             // 0..3 (wave-uniform)
    const int b = blockIdx.x >> 9;
    const int h = (blockIdx.x >> 2) & 127;
    const int g = blockIdx.x & 3;
    const int d0 = ((g << 2) + sg) << 3;   // owned d: d0..d0+7
    const float inv_n = 1.0f / 729.0f;

    unsigned win[9][5];
    float2 rs[5];
    #pragma unroll
    for (int f = 0; f < 5; ++f) rs[f] = ZER2;
    float local = 0.f;

    // prefetch step 0 (dd = d0-4)
    uint4 nx = make_uint4(0u, 0u, 0u, 0u);
    unsigned nx4 = 0u;
    {
        const int dd = d0 - 4;
        if ((unsigned)dd < 128u) {
            const unsigned* row = bufB + ((b * 128 + dd) * 128 + h) * 320;
            nx = *reinterpret_cast<const uint4*>(row + 4 * wp);
            nx4 = row[256 + wp];
        }
    }

    #pragma unroll
    for (int s = 0; s < 16; ++s) {
        const uint4 cx = nx;
        const unsigned cx4 = nx4;
        if (s < 15) {
            const int dd = d0 - 3 + s;
            if ((unsigned)dd < 128u) {
                const unsigned* row = bufB + ((b * 128 + dd) * 128 + h) * 320;
                nx = *reinterpret_cast<const uint4*>(row + 4 * wp);
                nx4 = row[256 + wp];
            } else {
                nx = make_uint4(0u, 0u, 0u, 0u); nx4 = 0u;
            }
        }

        const unsigned x[5] = {cx.x, cx.y, cx.z, cx.w, cx4};
        #pragma unroll
        for (int f = 0; f < 5; ++f) {
            if (s >= 9) {
                const float2 o = unpack_bf2(win[s % 9][f]);
                rs[f].x -= o.x; rs[f].y -= o.y;
            }
            const float2 nv = unpack_bf2(x[f]);
            rs[f].x += nv.x; rs[f].y += nv.y;
            win[s % 9][f] = x[f];
        }
        if (s >= 8) {
            const float uix = rs[0].x * inv_n, uiy = rs[0].y * inv_n;
            const float ujx = rs[1].x * inv_n, ujy = rs[1].y * inv_n;
            const float i2x = rs[2].x * inv_n - uix * uix;
            const float i2y = rs[2].y * inv_n - uiy * uiy;
            const float j2x = rs[3].x * inv_n - ujx * ujx;
            const float j2y = rs[3].y * inv_n - ujy * ujy;
            const float ijx = rs[4].x * inv_n - uix * ujx;
            const float ijy = rs[4].y * inv_n - uiy * ujy;
            local += ijx * ijx / (i2x * j2x + 1e-5f)
                   + ijy * ijy / (i2y * j2y + 1e-5f);
        }
    }

    __shared__ float lds[4];
    const float s = wave_block_reduce_partial(local, lds, t, 4);
    if (t == 0) nccPartial[blockIdx.x] = s;
}

// ---------------- Finalize ----------------
__global__ void finalize(const float* __restrict__ nccPartial, const float* __restrict__ regPartial,
                         float* __restrict__ out) {
    __shared__ float sdata[256];
    const int t = threadIdx.x;
    float a = 0.f;
    for (int i = t; i < 1024; i += 256) a += nccPartial[i];
    sdata[t] = a; __syncthreads();
    for (int s = 128; s > 0; s >>= 1) { if (t < s) sdata[t] += sdata[t + s]; __syncthreads(); }
    const float nccSum = sdata[0];
    __syncthreads();
    float bsum = 0.f;
    for (int i = t; i < 1024; i += 256) bsum += regPartial[i];
    sdata[t] = bsum; __syncthreads();
    for (int s = 128; s > 0; s >>= 1) { if (t < s) sdata[t] += sdata[t + s]; __syncthreads(); }
    if (t == 0) {
        const float reg = sdata[0];
        const float sim = -nccSum / (float)V;
        out[0] = sim + 0.01f * reg;
        out[1] = sim;
        out[2] = reg;
    }
}

extern "C" void kernel_launch(void* const* d_in, const int* in_sizes, int n_in,
                              void* d_out, int out_size, void* d_ws, size_t ws_size,
                              hipStream_t stream) {
    const float* warped = (const float*)d_in[0];
    const float* fixedv = (const float*)d_in[1];
    const float* flow   = (const float*)d_in[2];
    float* out = (float*)d_out;
    float* ws  = (float*)d_ws;

    // ws layout (floats): [0,1024) nccPartial | [1024,2048) regPartial | pad |
    //                     [16384, ...) bufB packed bf16 (2*128^3*5*2B ~= 42 MB)
    float* nccPartial = ws;
    float* regPartial = ws + 1024;
    unsigned* bufB = (unsigned*)(ws + 16384);

    // 1024 blocks = 4096 wh-waves (wave = (b, d, h-chunk of 8)); bending interleaved
    wh_bend<<<dim3(1024), dim3(256), 0, stream>>>(warped, fixedv, flow, bufB, regPartial);
    // 1024 blocks = (b, h, seg-group); 256 threads = w-pair x 4 d-segments
    ncc_d<<<dim3(1024), dim3(256), 0, stream>>>(bufB, nccPartial);
    finalize<<<dim3(1), dim3(256), 0, stream>>>(nccPartial, regPartial, out);
}

// Round 14
// 58.608 us; speedup vs baseline: 11.6320x; 1.2853x over previous
//
#include <hip/hip_runtime.h>

// RegistrationLoss: sim = -mean(NCC_9x9x9(warped, fixed)), reg = bending energy of flow,
// total = sim + 0.01*reg. Inputs f32: warped[2,1,128,128,128], fixed same, flow[2,3,128,128,128].
// Output: 3 floats [total, sim, reg].
//
// Round-14 structure (R11 + cross-wave role alternation):
//   R12: <=64 VGPR unreachable (spill storm). R13: single-wave interleave -> VGPR 236,
//   occupancy halved. Remaining lever: heterogeneous waves per SIMD.
//   wh_bend: identical blocks (4 waves). Wave role by parity r=(bid+wv)&1:
//            r==0 -> wh task first, bending slice second; r==1 -> reverse order.
//            Wave slot wv lands on SIMD wv%4, and co-resident blocks alternate parity,
//            so each SIMD hosts ~50/50 wh-phase (VMEM-stall-heavy) and bending-phase
//            (VALU-streaming) waves at all times -> bending fills wh's idle issue slots
//            WITHOUT merging streams into one wave (R13's VGPR explosion) and WITHOUT
//            block-type residency asymmetry (R7).
//   wh task: DPP W-views (wave_shr/shl zero-fill = zero-pad), products, W-box,
//            H-box f32 ring, bufB packed bf16 (42 MB). Same engine as R11.
//   bending: 12 float4-iters keyed to waveId; per-wave shfl reduce -> regPartial[4096].
//   ncc_d:  R11's version (D-box ring, 1-step prefetch, uint4+dword loads).
// bufB row layout (per (b,d,h), 320 unsigned = 1280 B):
//   [0,256): uint4{bf2(f0),bf2(f1),bf2(f2),bf2(f3)} per w-pair at 4*wp
//   [256,320): bf2(f4) dword per w-pair
// Lessons kept: no min-waves launch_bounds (R4/R12); no per-LANE conditional loads (R5);
// compile-time indices (rule #20). Tripwire: VGPR>128 => void.

#define DIM 128
#define V   4194304L      // 2*128^3
#define NVOL6 12582912L   // 6*128^3

#define ZER2 make_float2(0.f, 0.f)

__device__ __forceinline__ unsigned pack_bf2(float2 v) {
    unsigned ax = __float_as_uint(v.x), ay = __float_as_uint(v.y);
    ax = ax + 0x7fffu + ((ax >> 16) & 1u);      // round-to-nearest-even
    ay = ay + 0x7fffu + ((ay >> 16) & 1u);
    return (ax >> 16) | (ay & 0xffff0000u);
}
__device__ __forceinline__ float2 unpack_bf2(unsigned u) {
    return make_float2(__uint_as_float(u << 16), __uint_as_float(u & 0xffff0000u));
}

// DPP wave-wide lane shifts. wave_shr:1 (0x138): lane i <- lane i-1 (lane 0 -> 0).
// wave_shl:1 (0x130): lane i <- lane i+1 (lane 63 -> 0). bound_ctrl=true: zero-fill.
__device__ __forceinline__ float dpp_up1(float x) {
    return __int_as_float(__builtin_amdgcn_mov_dpp(__float_as_int(x), 0x138, 0xF, 0xF, true));
}
__device__ __forceinline__ float dpp_dn1(float x) {
    return __int_as_float(__builtin_amdgcn_mov_dpp(__float_as_int(x), 0x130, 0xF, 0xF, true));
}
__device__ __forceinline__ float2 dpp_up1_f2(float2 v) {
    return make_float2(dpp_up1(v.x), dpp_up1(v.y));
}
__device__ __forceinline__ float2 dpp_dn1_f2(float2 v) {
    return make_float2(dpp_dn1(v.x), dpp_dn1(v.y));
}

__device__ __forceinline__ float wave_reduce64(float v) {
    #pragma unroll
    for (int off = 32; off > 0; off >>= 1) v += __shfl_down(v, off, 64);
    return v;   // valid on lane 0
}

// ---------------- wh task body (one wave = one (b,d,h-chunk of 8) task) ----------------
__device__ __forceinline__ void wh_task(const float* __restrict__ I,
                                        const float* __restrict__ J,
                                        unsigned* __restrict__ bufB,
                                        int wid, int lane) {
    const int e = wid & 15;           // h-chunk
    const int d = (wid >> 4) & 127;
    const int b = wid >> 11;
    const int h0 = e << 3;
    const int w0 = lane << 1;
    const float* baseI = I + (b * 128 + d) * 16384 + w0;
    const float* baseJ = J + (b * 128 + d) * 16384 + w0;

    float2 win[9][5];
    float2 hs[5];
    #pragma unroll
    for (int f = 0; f < 5; ++f) hs[f] = ZER2;

    // 1-step prefetch of the center float2 (wave-uniform row guard)
    float2 na = ZER2, nb = ZER2;
    {
        const int h = h0 - 4;
        if ((unsigned)h < 128u) {
            na = *reinterpret_cast<const float2*>(baseI + h * 128);
            nb = *reinterpret_cast<const float2*>(baseJ + h * 128);
        }
    }

    #pragma unroll
    for (int s = 0; s < 16; ++s) {
        const float2 ci = na, cj = nb;
        if (s < 15) {
            const int h = h0 - 3 + s;
            if ((unsigned)h < 128u) {
                na = *reinterpret_cast<const float2*>(baseI + h * 128);
                nb = *reinterpret_cast<const float2*>(baseJ + h * 128);
            } else {
                na = ZER2; nb = ZER2;
            }
        }

        // 5 shifted W-views via DPP lane shifts (element offsets -4,-2,0,+2,+4)
        float2 iv[5], jv[5];
        iv[2] = ci;                jv[2] = cj;
        iv[1] = dpp_up1_f2(ci);    jv[1] = dpp_up1_f2(cj);
        iv[0] = dpp_up1_f2(iv[1]); jv[0] = dpp_up1_f2(jv[1]);
        iv[3] = dpp_dn1_f2(ci);    jv[3] = dpp_dn1_f2(cj);
        iv[4] = dpp_dn1_f2(iv[3]); jv[4] = dpp_dn1_f2(jv[3]);

        float2 v[5][5];
        #pragma unroll
        for (int o = 0; o < 5; ++o) {
            v[0][o] = iv[o];
            v[1][o] = jv[o];
            v[2][o] = make_float2(iv[o].x * iv[o].x, iv[o].y * iv[o].y);
            v[3][o] = make_float2(jv[o].x * jv[o].x, jv[o].y * jv[o].y);
            v[4][o] = make_float2(iv[o].x * jv[o].x, iv[o].y * jv[o].y);
        }

        #pragma unroll
        for (int f = 0; f < 5; ++f) {
            const float core = v[f][1].x + v[f][1].y + v[f][2].x + v[f][2].y
                             + v[f][3].x + v[f][3].y;
            float2 wb;
            wb.x = core + v[f][0].x + v[f][0].y + v[f][4].x;   // window w-4..w+4
            wb.y = core + v[f][0].y + v[f][4].x + v[f][4].y;   // window w-3..w+5
            if (s >= 9) { hs[f].x -= win[s % 9][f].x; hs[f].y -= win[s % 9][f].y; }
            hs[f].x += wb.x; hs[f].y += wb.y;
            win[s % 9][f] = wb;
        }

        if (s >= 8) {
            const int h_out = h0 + s - 8;
            unsigned* row = bufB + (((wid >> 4) << 7) + h_out) * 320;   // (b*128+d)*128 + h
            const uint4 pk = make_uint4(pack_bf2(hs[0]), pack_bf2(hs[1]),
                                        pack_bf2(hs[2]), pack_bf2(hs[3]));
            *reinterpret_cast<uint4*>(row + 4 * lane) = pk;
            row[256 + lane] = pack_bf2(hs[4]);
        }
    }
}

// ---------------- bending slice body (one wave = 12 float4-iters over flow) ----------------
__device__ __forceinline__ float bend_slice(const float* __restrict__ F, int waveId, int lane) {
    const float invS = 1.0f / 12386304.0f;   // 6*126*128*128  (i==j)
    const float invC = 1.0f / 12289536.0f;   // 6*127*126*128  (i!=j, both orderings)
    float local = 0.f;

    #pragma unroll 2
    for (int it = 0; it < 12; ++it) {
        const int tid = (waveId + it * 4096) * 64 + lane;   // [0, 3145728)
        const long e = (long)tid << 2;                       // element base (multiple of 4)
        const int r = (int)(e & 2097151);
        const int d = r >> 14;
        const int h = (r >> 7) & 127;
        const int w0 = r & 127;                              // 0,4,...,124

        const float* p = F + e;
        const int off4 = (w0 < 124) ? 4 : 0;
        const int oD  = (d < 127) ? 16384 : 0;
        const int oD2 = (d < 126) ? 32768 : 0;
        const int oH  = (h < 127) ? 128 : 0;
        const int oH2 = (h < 126) ? 256 : 0;

        const float4 a0  = *reinterpret_cast<const float4*>(p);
        const float2 s45 = *reinterpret_cast<const float2*>(p + off4);
        const float4 aD  = *reinterpret_cast<const float4*>(p + oD);
        const float  sD4 = (p + oD)[off4];
        const float4 aD2 = *reinterpret_cast<const float4*>(p + oD2);
        const float4 aH  = *reinterpret_cast<const float4*>(p + oH);
        const float  sH4 = (p + oH)[off4];
        const float4 aH2 = *reinterpret_cast<const float4*>(p + oH2);
        const float4 aDH = *reinterpret_cast<const float4*>(p + oD + oH);

        const float A0[6] = {a0.x, a0.y, a0.z, a0.w, s45.x, s45.y};
        const float AD[5] = {aD.x, aD.y, aD.z, aD.w, sD4};
        const float AH[5] = {aH.x, aH.y, aH.z, aH.w, sH4};
        const float AD2[4] = {aD2.x, aD2.y, aD2.z, aD2.w};
        const float AH2[4] = {aH2.x, aH2.y, aH2.z, aH2.w};
        const float ADH[4] = {aDH.x, aDH.y, aDH.z, aDH.w};

        const float mD2 = (d < 126) ? invS : 0.f;
        const float mH2 = (h < 126) ? invS : 0.f;
        const float cD  = (d < 126) ? 1.f : 0.f;
        const float cH  = (h < 126) ? 1.f : 0.f;
        const bool  vD  = d < 127, vH = h < 127;

        #pragma unroll
        for (int k = 0; k < 4; ++k) {
            const int wk = w0 + k;
            const float mW2 = (wk < 126) ? invS : 0.f;
            const float cW  = (wk < 126) ? 1.f : 0.f;
            const bool  vW  = wk < 127;

            const float xW = A0[k + 2] - 2.f * A0[k + 1] + A0[k];
            local += xW * xW * mW2;
            const float xD = AD2[k] - 2.f * AD[k] + A0[k];
            local += xD * xD * mD2;
            const float xH = AH2[k] - 2.f * AH[k] + A0[k];
            local += xH * xH * mH2;

            const float xDH = ADH[k] - AD[k] - AH[k] + A0[k];
            local += xDH * xDH * (((vD && vH) ? (cD + cH) : 0.f) * invC);
            const float xDW = AD[k + 1] - AD[k] - A0[k + 1] + A0[k];
            local += xDW * xDW * (((vD && vW) ? (cD + cW) : 0.f) * invC);
            const float xHW = AH[k + 1] - AH[k] - A0[k + 1] + A0[k];
            local += xHW * xHW * (((vH && vW) ? (cH + cW) : 0.f) * invC);
        }
    }
    return local;
}

// ---------------- Kernel 1: role-alternating wh + bending ----------------
__global__ __launch_bounds__(256) void wh_bend(const float* __restrict__ I,
                                               const float* __restrict__ J,
                                               const float* __restrict__ F,
                                               unsigned* __restrict__ bufB,
                                               float* __restrict__ regPartial) {
    const int lane = threadIdx.x & 63;
    const int wv   = threadIdx.x >> 6;
    const int bid  = blockIdx.x;
    const int waveId = (bid << 2) + wv;        // [0, 4096)
    const int r = (bid + wv) & 1;              // role parity: mixes roles within each SIMD

    float bendAcc;
    if (r == 0) {
        wh_task(I, J, bufB, waveId, lane);
        bendAcc = bend_slice(F, waveId, lane);
    } else {
        bendAcc = bend_slice(F, waveId, lane);
        wh_task(I, J, bufB, waveId, lane);
    }

    const float s = wave_reduce64(bendAcc);
    if (lane == 0) regPartial[waveId] = s;
}

// ---------------- Kernel 2: D-box + NCC + block reduce (R11 version) ----------------
__global__ __launch_bounds__(256) void ncc_d(const unsigned* __restrict__ bufB,
                                             float* __restrict__ nccPartial) {
    const int t = threadIdx.x;
    const int wp = t & 63;             // w-pair index
    const int sg = t >> 6;             // 0..3 (wave-uniform)
    const int b = blockIdx.x >> 9;
    const int h = (blockIdx.x >> 2) & 127;
    const int g = blockIdx.x & 3;
    const int d0 = ((g << 2) + sg) << 3;   // owned d: d0..d0+7
    const float inv_n = 1.0f / 729.0f;

    unsigned win[9][5];
    float2 rs[5];
    #pragma unroll
    for (int f = 0; f < 5; ++f) rs[f] = ZER2;
    float local = 0.f;

    // prefetch step 0 (dd = d0-4)
    uint4 nx = make_uint4(0u, 0u, 0u, 0u);
    unsigned nx4 = 0u;
    {
        const int dd = d0 - 4;
        if ((unsigned)dd < 128u) {
            const unsigned* row = bufB + ((b * 128 + dd) * 128 + h) * 320;
            nx = *reinterpret_cast<const uint4*>(row + 4 * wp);
            nx4 = row[256 + wp];
        }
    }

    #pragma unroll
    for (int s = 0; s < 16; ++s) {
        const uint4 cx = nx;
        const unsigned cx4 = nx4;
        if (s < 15) {
            const int dd = d0 - 3 + s;
            if ((unsigned)dd < 128u) {
                const unsigned* row = bufB + ((b * 128 + dd) * 128 + h) * 320;
                nx = *reinterpret_cast<const uint4*>(row + 4 * wp);
                nx4 = row[256 + wp];
            } else {
                nx = make_uint4(0u, 0u, 0u, 0u); nx4 = 0u;
            }
        }

        const unsigned x[5] = {cx.x, cx.y, cx.z, cx.w, cx4};
        #pragma unroll
        for (int f = 0; f < 5; ++f) {
            if (s >= 9) {
                const float2 o = unpack_bf2(win[s % 9][f]);
                rs[f].x -= o.x; rs[f].y -= o.y;
            }
            const float2 nv = unpack_bf2(x[f]);
            rs[f].x += nv.x; rs[f].y += nv.y;
            win[s % 9][f] = x[f];
        }
        if (s >= 8) {
            const float uix = rs[0].x * inv_n, uiy = rs[0].y * inv_n;
            const float ujx = rs[1].x * inv_n, ujy = rs[1].y * inv_n;
            const float i2x = rs[2].x * inv_n - uix * uix;
            const float i2y = rs[2].y * inv_n - uiy * uiy;
            const float j2x = rs[3].x * inv_n - ujx * ujx;
            const float j2y = rs[3].y * inv_n - ujy * ujy;
            const float ijx = rs[4].x * inv_n - uix * ujx;
            const float ijy = rs[4].y * inv_n - uiy * ujy;
            local += ijx * ijx / (i2x * j2x + 1e-5f)
                   + ijy * ijy / (i2y * j2y + 1e-5f);
        }
    }

    __shared__ float lds[4];
    #pragma unroll
    for (int off = 32; off > 0; off >>= 1) local += __shfl_down(local, off, 64);
    if ((t & 63) == 0) lds[t >> 6] = local;
    __syncthreads();
    if (t == 0) {
        float s = 0.f;
        for (int i = 0; i < 4; ++i) s += lds[i];
        nccPartial[blockIdx.x] = s;
    }
}

// ---------------- Finalize ----------------
__global__ void finalize(const float* __restrict__ nccPartial, const float* __restrict__ regPartial,
                         float* __restrict__ out) {
    __shared__ float sdata[256];
    const int t = threadIdx.x;
    float a = 0.f;
    for (int i = t; i < 1024; i += 256) a += nccPartial[i];
    sdata[t] = a; __syncthreads();
    for (int s = 128; s > 0; s >>= 1) { if (t < s) sdata[t] += sdata[t + s]; __syncthreads(); }
    const float nccSum = sdata[0];
    __syncthreads();
    float bsum = 0.f;
    for (int i = t; i < 4096; i += 256) bsum += regPartial[i];
    sdata[t] = bsum; __syncthreads();
    for (int s = 128; s > 0; s >>= 1) { if (t < s) sdata[t] += sdata[t + s]; __syncthreads(); }
    if (t == 0) {
        const float reg = sdata[0];
        const float sim = -nccSum / (float)V;
        out[0] = sim + 0.01f * reg;
        out[1] = sim;
        out[2] = reg;
    }
}

extern "C" void kernel_launch(void* const* d_in, const int* in_sizes, int n_in,
                              void* d_out, int out_size, void* d_ws, size_t ws_size,
                              hipStream_t stream) {
    const float* warped = (const float*)d_in[0];
    const float* fixedv = (const float*)d_in[1];
    const float* flow   = (const float*)d_in[2];
    float* out = (float*)d_out;
    float* ws  = (float*)d_ws;

    // ws layout (floats): [0,1024) nccPartial | [1024,5120) regPartial | pad |
    //                     [16384, ...) bufB packed bf16 (2*128^3*5*2B ~= 42 MB)
    float* nccPartial = ws;
    float* regPartial = ws + 1024;
    unsigned* bufB = (unsigned*)(ws + 16384);

    // 1024 identical blocks; wave role alternates by (bid+wv)&1 -> per-SIMD mix
    wh_bend<<<dim3(1024), dim3(256), 0, stream>>>(warped, fixedv, flow, bufB, regPartial);
    // 1024 blocks = (b, h, seg-group); 256 threads = w-pair x 4 d-segments
    ncc_d<<<dim3(1024), dim3(256), 0, stream>>>(bufB, nccPartial);
    finalize<<<dim3(1), dim3(256), 0, stream>>>(nccPartial, regPartial, out);
}

// Round 15
// 52.276 us; speedup vs baseline: 13.0409x; 1.1211x over previous
//
#include <hip/hip_runtime.h>

// RegistrationLoss: sim = -mean(NCC_9x9x9(warped, fixed)), reg = bending energy of flow,
// total = sim + 0.01*reg. Inputs f32: warped[2,1,128,128,128], fixed same, flow[2,3,128,128,128].
// Output: 3 floats [total, sim, reg].
//
// Round-15 structure (R11 + deep prefetch both phases):
//   R14 lesson: role-alternation neutral on kernel time, -5us on total (input locality).
//   Uniform phase order (wh then bend) restored. ncc_d is ~2-3us (bufB L3-resident);
//   wh_bend is 50 of 53.5us — all effort goes there.
//   Stall arithmetic: 1-deep prefetch = 2 outstanding loads vs ~900cy first-touch HBM
//   latency with ~240cy compute/step. Fix: 4-deep row prefetch (pa[4]/pb[4], static
//   indices under full unroll). R8's 2-deep null result was under the LDS version whose
//   lgkm write->read chain masked prefetch depth; DPP version waits on vmcnt only.
//   Bending: explicit 2-stage pipeline (load it+1, compute it) — runs after wh, so its
//   ~60-reg set reuses dead wh registers.
//   ncc_d:  R11's version (D-box ring, 1-step prefetch, uint4+dword loads).
// bufB row layout (per (b,d,h), 320 unsigned = 1280 B):
//   [0,256): uint4{bf2(f0),bf2(f1),bf2(f2),bf2(f3)} per w-pair at 4*wp
//   [256,320): bf2(f4) dword per w-pair
// Lessons kept: no min-waves launch_bounds (R4/R12); no per-LANE conditional loads (R5);
// no block-type mixing (R7); no single-wave stream merge (R13); compile-time indices
// (rule #20). Tripwire: VGPR>128 or WRITE >> 41 MB => void.

#define DIM 128
#define V   4194304L      // 2*128^3
#define NVOL6 12582912L   // 6*128^3

#define ZER2 make_float2(0.f, 0.f)

__device__ __forceinline__ unsigned pack_bf2(float2 v) {
    unsigned ax = __float_as_uint(v.x), ay = __float_as_uint(v.y);
    ax = ax + 0x7fffu + ((ax >> 16) & 1u);      // round-to-nearest-even
    ay = ay + 0x7fffu + ((ay >> 16) & 1u);
    return (ax >> 16) | (ay & 0xffff0000u);
}
__device__ __forceinline__ float2 unpack_bf2(unsigned u) {
    return make_float2(__uint_as_float(u << 16), __uint_as_float(u & 0xffff0000u));
}

// DPP wave-wide lane shifts. wave_shr:1 (0x138): lane i <- lane i-1 (lane 0 -> 0).
// wave_shl:1 (0x130): lane i <- lane i+1 (lane 63 -> 0). bound_ctrl=true: zero-fill.
__device__ __forceinline__ float dpp_up1(float x) {
    return __int_as_float(__builtin_amdgcn_mov_dpp(__float_as_int(x), 0x138, 0xF, 0xF, true));
}
__device__ __forceinline__ float dpp_dn1(float x) {
    return __int_as_float(__builtin_amdgcn_mov_dpp(__float_as_int(x), 0x130, 0xF, 0xF, true));
}
__device__ __forceinline__ float2 dpp_up1_f2(float2 v) {
    return make_float2(dpp_up1(v.x), dpp_up1(v.y));
}
__device__ __forceinline__ float2 dpp_dn1_f2(float2 v) {
    return make_float2(dpp_dn1(v.x), dpp_dn1(v.y));
}

__device__ __forceinline__ float wave_block_reduce_partial(float local, float* lds, int t, int nwaves) {
    #pragma unroll
    for (int off = 32; off > 0; off >>= 1) local += __shfl_down(local, off, 64);
    if ((t & 63) == 0) lds[t >> 6] = local;
    __syncthreads();
    float s = 0.f;
    if (t == 0) {
        for (int i = 0; i < nwaves; ++i) s += lds[i];
    }
    return s; // valid on t==0 only
}

// ---------------- bending: split load / compute for 2-stage pipeline ----------------
struct BendData {
    float4 a0, aD, aD2, aH, aH2, aDH;
    float2 s45;
    float  sD4, sH4;
    int    w0, d, h;
};

__device__ __forceinline__ BendData bend_load(const float* __restrict__ F, int tid) {
    BendData B;
    const long e = (long)tid << 2;                  // element base (multiple of 4)
    const int r = (int)(e & 2097151);
    B.d = r >> 14;
    B.h = (r >> 7) & 127;
    B.w0 = r & 127;                                 // 0,4,...,124

    const float* p = F + e;
    const int off4 = (B.w0 < 124) ? 4 : 0;
    const int oD  = (B.d < 127) ? 16384 : 0;
    const int oD2 = (B.d < 126) ? 32768 : 0;
    const int oH  = (B.h < 127) ? 128 : 0;
    const int oH2 = (B.h < 126) ? 256 : 0;

    B.a0  = *reinterpret_cast<const float4*>(p);
    B.s45 = *reinterpret_cast<const float2*>(p + off4);
    B.aD  = *reinterpret_cast<const float4*>(p + oD);
    B.sD4 = (p + oD)[off4];
    B.aD2 = *reinterpret_cast<const float4*>(p + oD2);
    B.aH  = *reinterpret_cast<const float4*>(p + oH);
    B.sH4 = (p + oH)[off4];
    B.aH2 = *reinterpret_cast<const float4*>(p + oH2);
    B.aDH = *reinterpret_cast<const float4*>(p + oD + oH);
    return B;
}

__device__ __forceinline__ float bend_compute(const BendData& B) {
    const float invS = 1.0f / 12386304.0f;   // 6*126*128*128  (i==j)
    const float invC = 1.0f / 12289536.0f;   // 6*127*126*128  (i!=j, both orderings)

    const float A0[6] = {B.a0.x, B.a0.y, B.a0.z, B.a0.w, B.s45.x, B.s45.y};
    const float AD[5] = {B.aD.x, B.aD.y, B.aD.z, B.aD.w, B.sD4};
    const float AH[5] = {B.aH.x, B.aH.y, B.aH.z, B.aH.w, B.sH4};
    const float AD2[4] = {B.aD2.x, B.aD2.y, B.aD2.z, B.aD2.w};
    const float AH2[4] = {B.aH2.x, B.aH2.y, B.aH2.z, B.aH2.w};
    const float ADH[4] = {B.aDH.x, B.aDH.y, B.aDH.z, B.aDH.w};

    const float mD2 = (B.d < 126) ? invS : 0.f;
    const float mH2 = (B.h < 126) ? invS : 0.f;
    const float cD  = (B.d < 126) ? 1.f : 0.f;
    const float cH  = (B.h < 126) ? 1.f : 0.f;
    const bool  vD  = B.d < 127, vH = B.h < 127;

    float local = 0.f;
    #pragma unroll
    for (int k = 0; k < 4; ++k) {
        const int wk = B.w0 + k;
        const float mW2 = (wk < 126) ? invS : 0.f;
        const float cW  = (wk < 126) ? 1.f : 0.f;
        const bool  vW  = wk < 127;

        const float xW = A0[k + 2] - 2.f * A0[k + 1] + A0[k];
        local += xW * xW * mW2;
        const float xD = AD2[k] - 2.f * AD[k] + A0[k];
        local += xD * xD * mD2;
        const float xH = AH2[k] - 2.f * AH[k] + A0[k];
        local += xH * xH * mH2;

        const float xDH = ADH[k] - AD[k] - AH[k] + A0[k];
        local += xDH * xDH * (((vD && vH) ? (cD + cH) : 0.f) * invC);
        const float xDW = AD[k + 1] - AD[k] - A0[k + 1] + A0[k];
        local += xDW * xDW * (((vD && vW) ? (cD + cW) : 0.f) * invC);
        const float xHW = AH[k + 1] - AH[k] - A0[k + 1] + A0[k];
        local += xHW * xHW * (((vH && vW) ? (cH + cW) : 0.f) * invC);
    }
    return local;
}

// ---------------- Kernel 1: wh (4-deep prefetch) then bending (2-stage pipeline) ----------------
__global__ __launch_bounds__(256) void wh_bend(const float* __restrict__ I,
                                               const float* __restrict__ J,
                                               const float* __restrict__ F,
                                               unsigned* __restrict__ bufB,
                                               float* __restrict__ regPartial) {
    // ================= phase 1: products + W-box + H-box -> bufB =================
    {
        const int lane = threadIdx.x & 63;
        const int wv   = threadIdx.x >> 6;
        const int wid  = (blockIdx.x << 2) + wv;   // [0, 4096)
        const int e = wid & 15;           // h-chunk of 8
        const int d = (wid >> 4) & 127;
        const int b = wid >> 11;
        const int h0 = e << 3;
        const int w0 = lane << 1;
        const float* baseI = I + (b * 128 + d) * 16384 + w0;
        const float* baseJ = J + (b * 128 + d) * 16384 + w0;

        float2 win[9][5];
        float2 hs[5];
        #pragma unroll
        for (int f = 0; f < 5; ++f) hs[f] = ZER2;

        // 4-deep row prefetch: slots hold rows h0-4+k for the next 4 steps
        float2 pa[4], pb[4];
        #pragma unroll
        for (int k = 0; k < 4; ++k) {
            const int h = h0 - 4 + k;
            if ((unsigned)h < 128u) {      // wave-uniform guard
                pa[k] = *reinterpret_cast<const float2*>(baseI + h * 128);
                pb[k] = *reinterpret_cast<const float2*>(baseJ + h * 128);
            } else {
                pa[k] = ZER2; pb[k] = ZER2;
            }
        }

        #pragma unroll
        for (int s = 0; s < 16; ++s) {
            const float2 ci = pa[s & 3], cj = pb[s & 3];   // row h0-4+s
            if (s < 12) {
                const int h = h0 + s;                       // row for step s+4
                if ((unsigned)h < 128u) {
                    pa[s & 3] = *reinterpret_cast<const float2*>(baseI + h * 128);
                    pb[s & 3] = *reinterpret_cast<const float2*>(baseJ + h * 128);
                } else {
                    pa[s & 3] = ZER2; pb[s & 3] = ZER2;
                }
            }

            // 5 shifted W-views via DPP lane shifts (element offsets -4,-2,0,+2,+4)
            float2 iv[5], jv[5];
            iv[2] = ci;                jv[2] = cj;
            iv[1] = dpp_up1_f2(ci);    jv[1] = dpp_up1_f2(cj);
            iv[0] = dpp_up1_f2(iv[1]); jv[0] = dpp_up1_f2(jv[1]);
            iv[3] = dpp_dn1_f2(ci);    jv[3] = dpp_dn1_f2(cj);
            iv[4] = dpp_dn1_f2(iv[3]); jv[4] = dpp_dn1_f2(jv[3]);

            float2 v[5][5];
            #pragma unroll
            for (int o = 0; o < 5; ++o) {
                v[0][o] = iv[o];
                v[1][o] = jv[o];
                v[2][o] = make_float2(iv[o].x * iv[o].x, iv[o].y * iv[o].y);
                v[3][o] = make_float2(jv[o].x * jv[o].x, jv[o].y * jv[o].y);
                v[4][o] = make_float2(iv[o].x * jv[o].x, iv[o].y * jv[o].y);
            }

            #pragma unroll
            for (int f = 0; f < 5; ++f) {
                const float core = v[f][1].x + v[f][1].y + v[f][2].x + v[f][2].y
                                 + v[f][3].x + v[f][3].y;
                float2 wb;
                wb.x = core + v[f][0].x + v[f][0].y + v[f][4].x;   // window w-4..w+4
                wb.y = core + v[f][0].y + v[f][4].x + v[f][4].y;   // window w-3..w+5
                if (s >= 9) { hs[f].x -= win[s % 9][f].x; hs[f].y -= win[s % 9][f].y; }
                hs[f].x += wb.x; hs[f].y += wb.y;
                win[s % 9][f] = wb;
            }

            if (s >= 8) {
                const int h_out = h0 + s - 8;
                unsigned* row = bufB + ((b * 128 + d) * 128 + h_out) * 320;
                const uint4 pk = make_uint4(pack_bf2(hs[0]), pack_bf2(hs[1]),
                                            pack_bf2(hs[2]), pack_bf2(hs[3]));
                *reinterpret_cast<uint4*>(row + 4 * lane) = pk;
                row[256 + lane] = pack_bf2(hs[4]);
            }
        }
    }

    // ================= phase 2: bending energy (2-stage pipelined) =================
    {
        float bendAcc = 0.f;
        BendData cur = bend_load(F, blockIdx.x * 256 + threadIdx.x);   // it = 0
        #pragma unroll
        for (int it = 0; it < 11; ++it) {
            BendData nxt = bend_load(F, (blockIdx.x + (it + 1) * 1024) * 256 + threadIdx.x);
            bendAcc += bend_compute(cur);
            cur = nxt;
        }
        bendAcc += bend_compute(cur);

        __shared__ float rl[4];
        const float s = wave_block_reduce_partial(bendAcc, rl, threadIdx.x, 4);
        if (threadIdx.x == 0) regPartial[blockIdx.x] = s;
    }
}

// ---------------- Kernel 2: D-box + NCC + block reduce (R11 version) ----------------
__global__ __launch_bounds__(256) void ncc_d(const unsigned* __restrict__ bufB,
                                             float* __restrict__ nccPartial) {
    const int t = threadIdx.x;
    const int wp = t & 63;             // w-pair index
    const int sg = t >> 6;             // 0..3 (wave-uniform)
    const int b = blockIdx.x >> 9;
    const int h = (blockIdx.x >> 2) & 127;
    const int g = blockIdx.x & 3;
    const int d0 = ((g << 2) + sg) << 3;   // owned d: d0..d0+7
    const float inv_n = 1.0f / 729.0f;

    unsigned win[9][5];
    float2 rs[5];
    #pragma unroll
    for (int f = 0; f < 5; ++f) rs[f] = ZER2;
    float local = 0.f;

    // prefetch step 0 (dd = d0-4)
    uint4 nx = make_uint4(0u, 0u, 0u, 0u);
    unsigned nx4 = 0u;
    {
        const int dd = d0 - 4;
        if ((unsigned)dd < 128u) {
            const unsigned* row = bufB + ((b * 128 + dd) * 128 + h) * 320;
            nx = *reinterpret_cast<const uint4*>(row + 4 * wp);
            nx4 = row[256 + wp];
        }
    }

    #pragma unroll
    for (int s = 0; s < 16; ++s) {
        const uint4 cx = nx;
        const unsigned cx4 = nx4;
        if (s < 15) {
            const int dd = d0 - 3 + s;
            if ((unsigned)dd < 128u) {
                const unsigned* row = bufB + ((b * 128 + dd) * 128 + h) * 320;
                nx = *reinterpret_cast<const uint4*>(row + 4 * wp);
                nx4 = row[256 + wp];
            } else {
                nx = make_uint4(0u, 0u, 0u, 0u); nx4 = 0u;
            }
        }

        const unsigned x[5] = {cx.x, cx.y, cx.z, cx.w, cx4};
        #pragma unroll
        for (int f = 0; f < 5; ++f) {
            if (s >= 9) {
                const float2 o = unpack_bf2(win[s % 9][f]);
                rs[f].x -= o.x; rs[f].y -= o.y;
            }
            const float2 nv = unpack_bf2(x[f]);
            rs[f].x += nv.x; rs[f].y += nv.y;
            win[s % 9][f] = x[f];
        }
        if (s >= 8) {
            const float uix = rs[0].x * inv_n, uiy = rs[0].y * inv_n;
            const float ujx = rs[1].x * inv_n, ujy = rs[1].y * inv_n;
            const float i2x = rs[2].x * inv_n - uix * uix;
            const float i2y = rs[2].y * inv_n - uiy * uiy;
            const float j2x = rs[3].x * inv_n - ujx * ujx;
            const float j2y = rs[3].y * inv_n - ujy * ujy;
            const float ijx = rs[4].x * inv_n - uix * ujx;
            const float ijy = rs[4].y * inv_n - uiy * ujy;
            local += ijx * ijx / (i2x * j2x + 1e-5f)
                   + ijy * ijy / (i2y * j2y + 1e-5f);
        }
    }

    __shared__ float lds[4];
    const float s = wave_block_reduce_partial(local, lds, t, 4);
    if (t == 0) nccPartial[blockIdx.x] = s;
}

// ---------------- Finalize ----------------
__global__ void finalize(const float* __restrict__ nccPartial, const float* __restrict__ regPartial,
                         float* __restrict__ out) {
    __shared__ float sdata[256];
    const int t = threadIdx.x;
    float a = 0.f;
    for (int i = t; i < 1024; i += 256) a += nccPartial[i];
    sdata[t] = a; __syncthreads();
    for (int s = 128; s > 0; s >>= 1) { if (t < s) sdata[t] += sdata[t + s]; __syncthreads(); }
    const float nccSum = sdata[0];
    __syncthreads();
    float bsum = 0.f;
    for (int i = t; i < 1024; i += 256) bsum += regPartial[i];
    sdata[t] = bsum; __syncthreads();
    for (int s = 128; s > 0; s >>= 1) { if (t < s) sdata[t] += sdata[t + s]; __syncthreads(); }
    if (t == 0) {
        const float reg = sdata[0];
        const float sim = -nccSum / (float)V;
        out[0] = sim + 0.01f * reg;
        out[1] = sim;
        out[2] = reg;
    }
}

extern "C" void kernel_launch(void* const* d_in, const int* in_sizes, int n_in,
                              void* d_out, int out_size, void* d_ws, size_t ws_size,
                              hipStream_t stream) {
    const float* warped = (const float*)d_in[0];
    const float* fixedv = (const float*)d_in[1];
    const float* flow   = (const float*)d_in[2];
    float* out = (float*)d_out;
    float* ws  = (float*)d_ws;

    // ws layout (floats): [0,1024) nccPartial | [1024,2048) regPartial | pad |
    //                     [16384, ...) bufB packed bf16 (2*128^3*5*2B ~= 42 MB)
    float* nccPartial = ws;
    float* regPartial = ws + 1024;
    unsigned* bufB = (unsigned*)(ws + 16384);

    // 1024 identical blocks = 4096 wh-waves; bending tail-fill in-phase
    wh_bend<<<dim3(1024), dim3(256), 0, stream>>>(warped, fixedv, flow, bufB, regPartial);
    // 1024 blocks = (b, h, seg-group); 256 threads = w-pair x 4 d-segments
    ncc_d<<<dim3(1024), dim3(256), 0, stream>>>(bufB, nccPartial);
    finalize<<<dim3(1), dim3(256), 0, stream>>>(nccPartial, regPartial, out);
}